// Round 1
// baseline (340.331 us; speedup 1.0000x reference)
//
#include <hip/hip_runtime.h>

#define N_NODES 8192
#define M_NEI   32
#define K_PTS   8
#define D       64
#define EPS_    1e-7f

// ---------------- prep: x_kernel rows (K x 64) ----------------
// x_kernel[0..6] = expmap(og, ptransp(og,og,kernel_points[1..7])), row 7 = og.
// ptransp(og,og,v) = v - v0*og  -> time comp zero, spatial = v[1:].
__global__ void prep_xk(const float* __restrict__ kp, float* __restrict__ xk) {
  int d = threadIdx.x;  // 64 threads
  for (int kk = 0; kk < K_PTS - 1; ++kk) {
    float v = kp[(kk + 1) * D + d];
    float p = (d == 0) ? 0.f : v * v;
    #pragma unroll
    for (int s = 1; s < 64; s <<= 1) p += __shfl_xor(p, s);
    float un = sqrtf(fmaxf(p, 1e-14f));
    float sh = sinhf(un) / un;
    xk[kk * D + d] = (d == 0) ? coshf(un) : sh * v;
  }
  xk[(K_PTS - 1) * D + d] = (d == 0) ? 1.f : 0.f;
}

// ---------------- prep: W transpose  Wt[d][k*64+o] = W[k][o][d] ----------------
__global__ void prep_wt(const float* __restrict__ W, float* __restrict__ Wt) {
  int idx = blockIdx.x * 256 + threadIdx.x;  // 32768 = 64*512
  int d = idx >> 9, ko = idx & 511;
  Wt[idx] = W[ko * D + d];
}

// ---------------- main ----------------
__launch_bounds__(256)
__global__ void kpa_main(const float* __restrict__ x, const int* __restrict__ nei,
                         const int* __restrict__ mask, const float* __restrict__ Wt,
                         const float* __restrict__ b, const float* __restrict__ scale,
                         const float* __restrict__ xk, float* __restrict__ out) {
  __shared__ __align__(16) float xr_s[D];
  __shared__ __align__(16) float xk_s[K_PTS * D];
  __shared__ __align__(16) float x0t[D * M_NEI];     // [d][m]
  __shared__ __align__(16) float dis_s[K_PTS * M_NEI];
  __shared__ __align__(16) float red[4 * D];

  const int n  = blockIdx.x;
  const int t  = threadIdx.x;
  const int w8 = t >> 6;     // wave id 0..3  -> m octet
  const int l  = t & 63;     // lane

  if (t < D) xr_s[t] = x[n * D + t];
  xk_s[t]       = xk[t];
  xk_s[t + 256] = xk[t + 256];
  __syncthreads();

  // ---- prologue: 8 lanes per neighbor m = t>>3, lane8 = t&7 owns d in [l8*8, +8)
  {
    const int m  = t >> 3;
    const int l8 = t & 7;
    const int d0 = l8 * 8;
    const int ni = nei[n * M_NEI + m];
    float y[8], xr[8];
    #pragma unroll
    for (int j = 0; j < 8; ++j) { y[j] = x[ni * D + d0 + j]; xr[j] = xr_s[d0 + j]; }
    // l_inner(xr, y)
    float p = 0.f;
    #pragma unroll
    for (int j = 0; j < 8; ++j) p += xr[j] * y[j];
    if (l8 == 0) p -= 2.f * xr[0] * y[0];
    p += __shfl_xor(p, 1); p += __shfl_xor(p, 2); p += __shfl_xor(p, 4);
    float alpha = fmaxf(-p, 1.f + EPS_);
    float dd  = acoshf(alpha);
    float den = sqrtf(fmaxf(alpha * alpha - 1.f, 1e-14f));
    float f   = dd / den;
    float v[8];
    #pragma unroll
    for (int j = 0; j < 8; ++j) v[j] = f * (y[j] - alpha * xr[j]);
    float v0 = __shfl(v[0], l & 56);          // lane8==0's v[0]
    float c  = -v0 / (1.f + xr_s[0]);
    float wv[8];
    float q = 0.f;
    #pragma unroll
    for (int j = 0; j < 8; ++j) { wv[j] = v[j] + c * xr[j]; q += wv[j] * wv[j]; }
    if (l8 == 0) q -= wv[0] * wv[0];          // spatial norm excludes d=0
    q += __shfl_xor(q, 1); q += __shfl_xor(q, 2); q += __shfl_xor(q, 4);
    float un = sqrtf(fmaxf(q, 1e-14f));
    float sh = sinhf(un) / un;
    float x0v[8];
    #pragma unroll
    for (int j = 0; j < 8; ++j) x0v[j] = sh * wv[j];
    if (l8 == 0) x0v[0] = coshf(un);
    #pragma unroll
    for (int j = 0; j < 8; ++j) x0t[(d0 + j) * M_NEI + m] = x0v[j];
    // dis[k][m]
    float msk = (float)mask[n * M_NEI + m];
    #pragma unroll
    for (int k = 0; k < K_PTS; ++k) {
      float pp = 0.f;
      #pragma unroll
      for (int j = 0; j < 8; ++j) pp += x0v[j] * xk_s[k * D + d0 + j];
      if (l8 == 0) pp -= 2.f * x0v[0] * xk_s[k * D];
      pp += __shfl_xor(pp, 1); pp += __shfl_xor(pp, 2); pp += __shfl_xor(pp, 4);
      float al = fmaxf(-pp, 1.f + EPS_);
      float dk = acoshf(al) * msk;
      if (l8 == k) dis_s[k * M_NEI + m] = dk;
    }
  }
  __syncthreads();

  // ---- main matmul: lane l -> k = l>>3, oct = l&7 (o in [oct*8,+8)); wave -> m octet
  const int k   = l >> 3;
  const int oct = l & 7;
  float acc[64];
  #pragma unroll
  for (int i = 0; i < 64; ++i) acc[i] = 0.f;
  const float* wp = Wt + l * 8;
  const float* xp = x0t + w8 * 8;
  #pragma unroll 2
  for (int d = 0; d < 64; ++d) {
    float4 xa = *(const float4*)(xp + d * 32);
    float4 xb = *(const float4*)(xp + d * 32 + 4);
    float4 wa = *(const float4*)(wp + d * 512);
    float4 wb = *(const float4*)(wp + d * 512 + 4);
    float xm[8] = {xa.x, xa.y, xa.z, xa.w, xb.x, xb.y, xb.z, xb.w};
    float wo[8] = {wa.x, wa.y, wa.z, wa.w, wb.x, wb.y, wb.z, wb.w};
    #pragma unroll
    for (int mi = 0; mi < 8; ++mi)
      #pragma unroll
      for (int oj = 0; oj < 8; ++oj)
        acc[mi * 8 + oj] += xm[mi] * wo[oj];
  }
  // bias
  #pragma unroll
  for (int oj = 0; oj < 8; ++oj) {
    float bvj = b[k * D + oct * 8 + oj];
    #pragma unroll
    for (int mi = 0; mi < 8; ++mi) acc[mi * 8 + oj] += bvj;
  }

  const float es = expf(scale[k]);
  float outacc[8];
  #pragma unroll
  for (int oj = 0; oj < 8; ++oj) outacc[oj] = 0.f;

  #pragma unroll
  for (int mi = 0; mi < 8; ++mi) {
    const int m = w8 * 8 + mi;
    float dm = dis_s[k * M_NEI + m];
    float h0 = __shfl(acc[mi * 8 + 0], l & 56);   // o==0 value of this k-group
    float nar2 = 0.f;
    #pragma unroll
    for (int oj = 0; oj < 8; ++oj) nar2 += acc[mi * 8 + oj] * acc[mi * 8 + oj];
    if (oct == 0) nar2 -= acc[mi * 8] * acc[mi * 8];
    nar2 += __shfl_xor(nar2, 1); nar2 += __shfl_xor(nar2, 2); nar2 += __shfl_xor(nar2, 4);
    float time = es / (1.f + expf(-h0)) + 1.0001f;
    float s  = (time * time - 1.f) / fmaxf(nar2, 1e-8f);
    float sq = sqrtf(s);
    float yv[8];
    #pragma unroll
    for (int oj = 0; oj < 8; ++oj) yv[oj] = dm * (acc[mi * 8 + oj] * sq);
    if (oct == 0) yv[0] = dm * time;
    // sum over k (lanes differ in bits 3..5)
    #pragma unroll
    for (int oj = 0; oj < 8; ++oj) {
      float z = yv[oj];
      z += __shfl_xor(z, 8); z += __shfl_xor(z, 16); z += __shfl_xor(z, 32);
      yv[oj] = z;
    }
    // l_inner(ave,ave) over o (reduce over oct groups)
    float ip = 0.f;
    #pragma unroll
    for (int oj = 0; oj < 8; ++oj) ip += yv[oj] * yv[oj];
    if (oct == 0) ip -= 2.f * yv[0] * yv[0];
    ip += __shfl_xor(ip, 1); ip += __shfl_xor(ip, 2); ip += __shfl_xor(ip, 4);
    float rin = 1.f / sqrtf(fmaxf(fabsf(ip), 1e-8f));
    #pragma unroll
    for (int oj = 0; oj < 8; ++oj) outacc[oj] += yv[oj] * rin;
  }
  if (l < 8) {
    #pragma unroll
    for (int oj = 0; oj < 8; ++oj) red[w8 * D + l * 8 + oj] = outacc[oj];
  }
  __syncthreads();
  if (t < D) {
    float sm = red[t] + red[D + t] + red[2 * D + t] + red[3 * D + t];
    float mv = sm * (1.f / 32.f);
    float ip = (t == 0) ? -mv * mv : mv * mv;
    #pragma unroll
    for (int s2 = 1; s2 < 64; s2 <<= 1) ip += __shfl_xor(ip, s2);
    out[n * D + t] = mv / sqrtf(fmaxf(fabsf(ip), 1e-8f));
  }
}

extern "C" void kernel_launch(void* const* d_in, const int* in_sizes, int n_in,
                              void* d_out, int out_size, void* d_ws, size_t ws_size,
                              hipStream_t stream) {
  const float* x     = (const float*)d_in[0];
  const int*   nei   = (const int*)d_in[1];
  const int*   mask  = (const int*)d_in[2];
  const float* W     = (const float*)d_in[3];
  const float* b     = (const float*)d_in[4];
  const float* scale = (const float*)d_in[5];
  const float* kp    = (const float*)d_in[6];
  float* out = (float*)d_out;

  float* Wt = (float*)d_ws;            // 64*512 floats = 128 KiB
  float* xk = Wt + 64 * 512;           // 8*64 floats

  prep_wt<<<128, 256, 0, stream>>>(W, Wt);
  prep_xk<<<1, 64, 0, stream>>>(kp, xk);
  kpa_main<<<N_NODES, 256, 0, stream>>>(x, nei, mask, Wt, b, scale, xk, out);
}